// Round 3
// baseline (141.163 us; speedup 1.0000x reference)
//
#include <hip/hip_runtime.h>
#include <hip/hip_bf16.h>

// PAM module: B=4, N=4096 (64x64), C=64.
// out[b,n,c] = gamma * sum_m softmax_row(q@k^T)[m,n] * v[m,c] + x[b,n,c]
//
// bf16 MFMA; energy recomputed. log2e folded into Wq/bq; softmax normalizer
// folded into MFMA C-init (lr = -log2(rowsum)). PV uses K=16 MFMA so the
// P fragment is built IN REGISTERS from the QK output (no LDS, no shuffles).
//  k0z: W -> W^T bf16 (Wq scaled by log2e), zero s-buffer
//  k1 : per-projection blocks (grid 768): q,k row-major bf16; v^T [c][n] bf16
//  k2 : partial rowsums s[m] += sum_n exp2(e') (n-split 8, atomic, dbuf LDS)
//  r2 : lr = -log2(s) ; out <- x
//  k3 : out += gamma * exp2(e'+lr) @ v (m-split 8, atomic, dbuf LDS, reg-P)

typedef __attribute__((ext_vector_type(8))) short short8;
typedef __attribute__((ext_vector_type(4))) short short4b;
typedef __attribute__((ext_vector_type(4))) float f32x4;
typedef __attribute__((ext_vector_type(4))) unsigned int u32x4;
typedef __attribute__((ext_vector_type(2))) unsigned int u32x2;

#define DEV static __device__ __forceinline__
#define LOG2E 1.4426950408889634f

DEV unsigned short f2bf(float f) {
    __hip_bfloat16 h = __float2bfloat16(f);
    return __builtin_bit_cast(unsigned short, h);
}
DEV unsigned int pack2(float lo, float hi) {
    return (unsigned int)f2bf(lo) | ((unsigned int)f2bf(hi) << 16);
}
DEV f32x4 MFMA32(short8 a, short8 b, f32x4 c) {
    return __builtin_amdgcn_mfma_f32_16x16x32_bf16(a, b, c, 0, 0, 0);
}
DEV f32x4 MFMA16(short4b a, short4b b, f32x4 c) {
#if __has_builtin(__builtin_amdgcn_mfma_f32_16x16x16_bf16)
    return __builtin_amdgcn_mfma_f32_16x16x16_bf16(a, b, c, 0, 0, 0);
#elif __has_builtin(__builtin_amdgcn_mfma_f32_16x16x16bf16_1k)
    return __builtin_amdgcn_mfma_f32_16x16x16bf16_1k(a, b, c, 0, 0, 0);
#else
    f32x4 d = c;
    asm volatile("v_mfma_f32_16x16x16_bf16 %0, %1, %2, %0" : "+v"(d) : "v"(a), "v"(b));
    return d;
#endif
}
DEV float EXP2(float x) {
#if __has_builtin(__builtin_amdgcn_exp2f)
    return __builtin_amdgcn_exp2f(x);
#else
    return exp2f(x);
#endif
}

// ws layout (bytes)
#define OFF_Q    0u          // [16384][64] bf16 = 2 MB  (q' = log2e * (xWq+bq))
#define OFF_K    2097152u    // [16384][64] bf16 = 2 MB
#define OFF_VT   4194304u    // [4][64][4096] bf16 = 2 MB
#define OFF_WT   6291456u    // [3][64][64] bf16 = 24 KB
#define OFF_S    6316032u    // [16384] f32 = 64 KB (row sums, atomic)
#define OFF_LR   6381568u    // [16384] f32 = 64 KB (lr = -log2 s)

// ---------------- k0z: weight transpose (+log2e on Wq) + zero s ----------------
__global__ __launch_bounds__(256) void k0z(const float* __restrict__ Wq,
                                           const float* __restrict__ Wk,
                                           const float* __restrict__ Wv,
                                           unsigned short* __restrict__ wt,
                                           float* __restrict__ sbuf) {
    int e = blockIdx.x * 256 + threadIdx.x;   // grid 64 -> [0,16384)
    sbuf[e] = 0.0f;
    if (e < 3 * 4096) {
        int w3 = e >> 12, rem = e & 4095, f = rem >> 6, c = rem & 63;
        const float* W = (w3 == 0) ? Wq : (w3 == 1) ? Wk : Wv;
        float s = (w3 == 0) ? LOG2E : 1.0f;
        wt[e] = f2bf(W[c * 64 + f] * s);   // wt[w3][f][c] = W[c][f] * s
    }
}

// ---------------- k1: projections, one projection per block (grid 768) ----------------
__global__ __launch_bounds__(256) void k1_proj(const float* __restrict__ x,
                                               const unsigned short* __restrict__ wt,
                                               const float* __restrict__ bq,
                                               const float* __restrict__ bk,
                                               const float* __restrict__ bv,
                                               unsigned short* __restrict__ qg,
                                               unsigned short* __restrict__ kg,
                                               unsigned short* __restrict__ vtg) {
    __shared__ __align__(16) char XT[8192];
    __shared__ __align__(16) char WT1[8192];
    __shared__ __align__(16) char VTILE[9216];
    int t = threadIdx.x, blk = blockIdx.x;
    int w3 = blk >> 8, rb = blk & 255;

    {   // stage x tile (fp32 -> bf16, swizzled)
        int m = t >> 2, q4 = t & 3;
        const f32x4* xs = (const f32x4*)(x + (size_t)(rb * 64 + m) * 64 + q4 * 16);
        f32x4 fa = xs[0], f2 = xs[1], fc = xs[2], fd = xs[3];
        u32x4 u0 = { pack2(fa[0],fa[1]), pack2(fa[2],fa[3]), pack2(f2[0],f2[1]), pack2(f2[2],f2[3]) };
        u32x4 u1 = { pack2(fc[0],fc[1]), pack2(fc[2],fc[3]), pack2(fd[0],fd[1]), pack2(fd[2],fd[3]) };
        int sw = (m & 7) << 4;
        *(u32x4*)(XT + m * 128 + ((q4 * 32) ^ sw)) = u0;
        *(u32x4*)(XT + m * 128 + ((q4 * 32 + 16) ^ sw)) = u1;
    }
    {   // stage this block's W^T
        int f = t >> 2, q4 = t & 3;
        const u32x4* s = (const u32x4*)(wt + w3 * 4096 + f * 64 + q4 * 16);
        u32x4 u0 = s[0], u1 = s[1];
        int sw = (f & 7) << 4;
        *(u32x4*)(WT1 + f * 128 + ((q4 * 32) ^ sw)) = u0;
        *(u32x4*)(WT1 + f * 128 + ((q4 * 32 + 16) ^ sw)) = u1;
    }
    __syncthreads();

    int lane = t & 63, wid = t >> 6, g = lane >> 4, ln = lane & 15;
    int arow = wid * 16 + ln;
    short8 a0 = *(const short8*)(XT + arow * 128 + ((16 * g) ^ ((arow & 7) << 4)));
    short8 a1 = *(const short8*)(XT + arow * 128 + ((64 + 16 * g) ^ ((arow & 7) << 4)));
    const float* bias = (w3 == 0) ? bq : (w3 == 1) ? bk : bv;
    float bscale = (w3 == 0) ? LOG2E : 1.0f;

    #pragma unroll
    for (int fb = 0; fb < 4; ++fb) {
        int frow = fb * 16 + ln;
        short8 b0 = *(const short8*)(WT1 + frow * 128 + ((16 * g) ^ ((frow & 7) << 4)));
        short8 b1 = *(const short8*)(WT1 + frow * 128 + ((64 + 16 * g) ^ ((frow & 7) << 4)));
        f32x4 acc = {0.f, 0.f, 0.f, 0.f};
        acc = MFMA32(a0, b0, acc);
        acc = MFMA32(a1, b1, acc);
        float bval = bias[frow] * bscale;
        if (w3 < 2) {
            unsigned short* dst = (w3 == 0) ? qg : kg;
            int gr = rb * 64 + wid * 16 + 4 * g;
            #pragma unroll
            for (int r = 0; r < 4; ++r)
                dst[(size_t)(gr + r) * 64 + frow] = f2bf(acc[r] + bval);
        } else {
            unsigned short* vt = (unsigned short*)VTILE;
            int mloc = wid * 16 + 4 * g;
            #pragma unroll
            for (int r = 0; r < 4; ++r)
                vt[frow * 72 + mloc + r] = f2bf(acc[r] + bval);
        }
    }
    if (w3 == 2) {   // block-uniform branch
        __syncthreads();
        int f = t >> 2, mq = t & 3;
        u32x4 u0 = *(const u32x4*)(VTILE + f * 144 + mq * 32);
        u32x4 u1 = *(const u32x4*)(VTILE + f * 144 + mq * 32 + 16);
        int b = rb >> 6, n0 = (rb & 63) * 64;
        unsigned short* dst = vtg + (size_t)b * 262144 + f * 4096 + n0 + mq * 16;
        *(u32x4*)(dst) = u0;
        *(u32x4*)(dst + 8) = u1;
    }
}

// ---------------- k2: partial row sums (n-split 8, dbuf, 1 barrier/iter) ----------------
// grid 2048: blk = b*512 + ns*64 + mb. Block: 64 m x 512 n, 16 chunks of 32 n.
__global__ __launch_bounds__(256, 8) void k2_rowsum(const unsigned short* __restrict__ qg,
                                                    const unsigned short* __restrict__ kg,
                                                    float* __restrict__ sbuf) {
    __shared__ __align__(16) char QT[8192];
    __shared__ __align__(16) char KT2[2][4096];
    int t = threadIdx.x, blk = blockIdx.x;
    int b = blk >> 9, ns = (blk >> 6) & 7, mb = blk & 63;
    int m0 = mb * 64, nbase = ns * 512;

    {   // stage pinned q tile (64 m rows)
        int row = t >> 2, q4 = t & 3, sw = (row & 7) << 4;
        const u32x4* s = (const u32x4*)(qg + (size_t)(b * 4096 + m0 + row) * 64 + q4 * 16);
        u32x4 u0 = s[0], u1 = s[1];
        *(u32x4*)(QT + row * 128 + ((q4 * 32) ^ sw)) = u0;
        *(u32x4*)(QT + row * 128 + ((q4 * 32 + 16) ^ sw)) = u1;
    }
    int srow = t >> 3, sb = t & 7, ssw = (srow & 7) << 4;   // 32 rows x 8 x 16B
    const unsigned short* kbase = kg + (size_t)(b * 4096 + nbase) * 64;
    {   // stage k chunk 0
        u32x4 u = *(const u32x4*)(kbase + srow * 64 + sb * 8);
        *(u32x4*)(KT2[0] + srow * 128 + ((sb * 16) ^ ssw)) = u;
    }
    __syncthreads();

    int lane = t & 63, wid = t >> 6, g = lane >> 4, ln = lane & 15;
    int arow = wid * 16 + ln;
    short8 a0 = *(const short8*)(QT + arow * 128 + ((16 * g) ^ ((arow & 7) << 4)));
    short8 a1 = *(const short8*)(QT + arow * 128 + ((64 + 16 * g) ^ ((arow & 7) << 4)));

    float acc0 = 0.f, acc1 = 0.f, acc2 = 0.f, acc3 = 0.f;
    int buf = 0;
    u32x4 pf;
    for (int nc = 0; nc < 16; ++nc) {
        if (nc < 15)
            pf = *(const u32x4*)(kbase + (size_t)((nc + 1) * 32 + srow) * 64 + sb * 8);
        const char* kt = KT2[buf];
        #pragma unroll
        for (int j = 0; j < 2; ++j) {
            int brow = j * 16 + ln, bsw = (brow & 7) << 4;
            short8 kb0 = *(const short8*)(kt + brow * 128 + ((16 * g) ^ bsw));
            short8 kb1 = *(const short8*)(kt + brow * 128 + ((64 + 16 * g) ^ bsw));
            f32x4 e = {0.f, 0.f, 0.f, 0.f};
            e = MFMA32(a0, kb0, e);
            e = MFMA32(a1, kb1, e);
            acc0 += EXP2(e[0]); acc1 += EXP2(e[1]);
            acc2 += EXP2(e[2]); acc3 += EXP2(e[3]);
        }
        if (nc < 15)
            *(u32x4*)(KT2[buf ^ 1] + srow * 128 + ((sb * 16) ^ ssw)) = pf;
        __syncthreads();
        buf ^= 1;
    }
    #pragma unroll
    for (int msk = 1; msk < 16; msk <<= 1) {
        acc0 += __shfl_xor(acc0, msk);
        acc1 += __shfl_xor(acc1, msk);
        acc2 += __shfl_xor(acc2, msk);
        acc3 += __shfl_xor(acc3, msk);
    }
    if (ln == 0) {
        float* base = sbuf + b * 4096 + m0 + wid * 16 + 4 * g;
        unsafeAtomicAdd(base + 0, acc0);
        unsafeAtomicAdd(base + 1, acc1);
        unsafeAtomicAdd(base + 2, acc2);
        unsafeAtomicAdd(base + 3, acc3);
    }
}

// ---------------- r2: lr = -log2(s) ; out <- x ----------------
__global__ __launch_bounds__(256) void r2_init(const float* __restrict__ sbuf,
                                               float* __restrict__ lrbuf,
                                               const float* __restrict__ x,
                                               float* __restrict__ outp) {
    int tid = blockIdx.x * 256 + threadIdx.x;   // grid 1024
    if (tid < 16384) lrbuf[tid] = -__log2f(sbuf[tid]);
    f32x4 v = *(const f32x4*)(x + 4 * (size_t)tid);
    *(f32x4*)(outp + 4 * (size_t)tid) = v;
}

// ---------------- k3: out += gamma * exp2(e'+lr) @ v  (m-split 8, reg-P) ----------------
// grid 2048: blk = b*512 + ms*64 + nb. Block: 64 n, 32 chunks of 16 m.
__global__ __launch_bounds__(256, 8) void k3_out(const unsigned short* __restrict__ qg,
                                                 const unsigned short* __restrict__ kg,
                                                 const unsigned short* __restrict__ vtg,
                                                 const float* __restrict__ lrbuf,
                                                 const float* __restrict__ gamma,
                                                 float* __restrict__ outp) {
    __shared__ __align__(16) char KT[8192];       // pinned [64 n][128B c] swz
    __shared__ __align__(16) char QT2[2][2048];   // dbuf [16 m][128B c] swz
    __shared__ __align__(16) char VT2[2][2560];   // dbuf [64 c][40B m-pad]
    int t = threadIdx.x, blk = blockIdx.x;
    int b = blk >> 9, ms = (blk >> 6) & 7, nb = blk & 63;
    int n0 = nb * 64, mbase = ms * 512;

    {   // stage pinned k tile
        int row = t >> 2, q4 = t & 3, sw = (row & 7) << 4;
        const u32x4* s = (const u32x4*)(kg + (size_t)(b * 4096 + n0 + row) * 64 + q4 * 16);
        u32x4 u0 = s[0], u1 = s[1];
        *(u32x4*)(KT + row * 128 + ((q4 * 32) ^ sw)) = u0;
        *(u32x4*)(KT + row * 128 + ((q4 * 32 + 16) ^ sw)) = u1;
    }
    int qrow = t >> 4, qh = t & 15;   // 16 rows x 16 x 8B
    int vc = t >> 2, vq = t & 3;      // 64 rows x 4 x 8B
    int qssw = (qrow & 7) << 4;
    const unsigned short* qbase = qg + (size_t)(b * 4096 + mbase) * 64;
    const unsigned short* vbase = vtg + (size_t)b * 262144 + (size_t)vc * 4096 + mbase;
    {   // stage chunk 0
        u32x2 qu = *(const u32x2*)(qbase + qrow * 64 + qh * 4);
        *(u32x2*)(QT2[0] + qrow * 128 + ((qh * 8) ^ qssw)) = qu;
        u32x2 vu = *(const u32x2*)(vbase + vq * 4);
        *(u32x2*)(VT2[0] + vc * 40 + vq * 8) = vu;
    }
    int lane = t & 63, wid = t >> 6, g = lane >> 4, ln = lane & 15;
    const float* lrb = lrbuf + b * 4096 + mbase + 4 * g;
    f32x4 lcur = *(const f32x4*)(lrb);
    __syncthreads();

    int krow = wid * 16 + ln, ksw = (krow & 7) << 4;
    short8 kb0 = *(const short8*)(KT + krow * 128 + ((16 * g) ^ ksw));
    short8 kb1 = *(const short8*)(KT + krow * 128 + ((64 + 16 * g) ^ ksw));

    f32x4 z = {0.f, 0.f, 0.f, 0.f};
    f32x4 oacc[4] = {z, z, z, z};
    int qsw = (ln & 7) << 4;
    int buf = 0;
    u32x2 qpf, vpf;
    f32x4 lnext;

    for (int mc = 0; mc < 32; ++mc) {
        if (mc < 31) {   // prefetch chunk mc+1 into regs
            qpf = *(const u32x2*)(qbase + (size_t)((mc + 1) * 16 + qrow) * 64 + qh * 4);
            vpf = *(const u32x2*)(vbase + (mc + 1) * 16 + vq * 4);
            lnext = *(const f32x4*)(lrb + (mc + 1) * 16);
        }
        const char* qt = QT2[buf];
        const char* vt = VT2[buf];
        // QK^T for this 16-m chunk; C-init = lr  ->  p = exp2(e)
        short8 as0 = *(const short8*)(qt + ln * 128 + ((16 * g) ^ qsw));
        short8 as1 = *(const short8*)(qt + ln * 128 + ((64 + 16 * g) ^ qsw));
        f32x4 e = MFMA32(as1, kb1, MFMA32(as0, kb0, lcur));
        float p0 = EXP2(e[0]), p1 = EXP2(e[1]), p2 = EXP2(e[2]), p3 = EXP2(e[3]);
        u32x2 pw = { pack2(p0, p1), pack2(p2, p3) };
        short4b pa = __builtin_bit_cast(short4b, pw);   // K=16 A-frag: in-register!
        #pragma unroll
        for (int fb = 0; fb < 4; ++fb) {
            short4b vb = *(const short4b*)(vt + (fb * 16 + ln) * 40 + g * 8);
            oacc[fb] = MFMA16(pa, vb, oacc[fb]);
        }
        if (mc < 31) {   // write next chunk into other buffer
            *(u32x2*)(QT2[buf ^ 1] + qrow * 128 + ((qh * 8) ^ qssw)) = qpf;
            *(u32x2*)(VT2[buf ^ 1] + vc * 40 + vq * 8) = vpf;
            lcur = lnext;
        }
        __syncthreads();
        buf ^= 1;
    }

    float gm = gamma[0];
    int nr = b * 4096 + n0 + wid * 16 + 4 * g;
    #pragma unroll
    for (int fb = 0; fb < 4; ++fb) {
        #pragma unroll
        for (int r = 0; r < 4; ++r)
            unsafeAtomicAdd(outp + (size_t)(nr + r) * 64 + fb * 16 + ln, gm * oacc[fb][r]);
    }
}

extern "C" void kernel_launch(void* const* d_in, const int* in_sizes, int n_in,
                              void* d_out, int out_size, void* d_ws, size_t ws_size,
                              hipStream_t stream) {
    const float* x  = (const float*)d_in[0];
    const float* Wq = (const float*)d_in[1];
    const float* bq = (const float*)d_in[2];
    const float* Wk = (const float*)d_in[3];
    const float* bk = (const float*)d_in[4];
    const float* Wv = (const float*)d_in[5];
    const float* bv = (const float*)d_in[6];
    const float* gm = (const float*)d_in[7];
    char* ws = (char*)d_ws;
    float* outp = (float*)d_out;

    unsigned short* qg  = (unsigned short*)(ws + OFF_Q);
    unsigned short* kg  = (unsigned short*)(ws + OFF_K);
    unsigned short* vtg = (unsigned short*)(ws + OFF_VT);
    unsigned short* wt  = (unsigned short*)(ws + OFF_WT);
    float* sbuf         = (float*)(ws + OFF_S);
    float* lrbuf        = (float*)(ws + OFF_LR);

    k0z<<<64, 256, 0, stream>>>(Wq, Wk, Wv, wt, sbuf);
    k1_proj<<<768, 256, 0, stream>>>(x, wt, bq, bk, bv, qg, kg, vtg);
    k2_rowsum<<<2048, 256, 0, stream>>>(qg, kg, sbuf);
    r2_init<<<1024, 256, 0, stream>>>(sbuf, lrbuf, x, outp);
    k3_out<<<2048, 256, 0, stream>>>(qg, kg, vtg, lrbuf, gm, outp);
}